// Round 8
// baseline (366.475 us; speedup 1.0000x reference)
//
#include <hip/hip_runtime.h>
#include <hip/hip_bf16.h>

#define DNUM 64
#define LNUM 64
#define SNUM 10
#define QNUM 30
#define SPC  40
#define DIM  128
#define QPD  (LNUM*QNUM)    // 1920 queries per domain
#define SPD  (LNUM*SNUM)    // 640 supports per domain
#define PAIRS 32            // 32 class-pair tiles (2 classes x 16 rows each)
#define BPD  (QPD/64)       // 30 blocks per domain (64 queries/block)
#define NBLK (DNUM*BPD)     // 1920 blocks x 4 waves = 7680 waves
#define LOG2E 1.44269504088896340736f

typedef __bf16 bf16x8 __attribute__((ext_vector_type(8)));
typedef float  f32x16 __attribute__((ext_vector_type(16)));
typedef unsigned int u32;
typedef unsigned short u16;

#if __has_builtin(__builtin_amdgcn_exp2f)
#define EXP2(x) __builtin_amdgcn_exp2f(x)
#else
#define EXP2(x) exp2f(x)
#endif

static __device__ __forceinline__ u32 f2bf(float x) {
    __bf16 h = (__bf16)x;
    return (u32)__builtin_bit_cast(u16, h);
}

// ---------------- kernel 1: normalize supports (x log2e) -> 32x32 A-frag order
// Tile p of domain d holds classes 2p (rows 0..9) and 2p+1 (rows 16..25);
// rows 10..15/26..31 are pad (never stored, never read). 16 B units:
// unit ((d*32+p)*8 + i)*64 + h*32 + m holds A[m][k=i*16+h*8 .. +7], so the
// main kernel's lane l (m=l&31, h=l>>5) reads frag i as one dwordx4 at
// tile_base + i*1024 + l*16 — consecutive lanes, consecutive 16 B. Supports
// carry the log2e factor so the main kernel uses native exp2. (verified R7)
__global__ __launch_bounds__(256)
void norm_sup(const float* __restrict__ emb, u16* __restrict__ sws)
{
    const int hw  = (blockIdx.x * 256 + threadIdx.x) >> 5;  // support row id
    const int sub = threadIdx.x & 31;                       // k = sub*4 .. +3
    const int d = hw / SPD, s = hw % SPD;
    const int c = s / SNUM, r = s % SNUM;
    const float4 v = *(const float4*)(emb + ((size_t)d * (LNUM * SPC) + c * SPC + r) * DIM + sub * 4);
    float ss = v.x*v.x + v.y*v.y + v.z*v.z + v.w*v.w;
    #pragma unroll
    for (int off = 16; off >= 1; off >>= 1) ss += __shfl_xor(ss, off);
    const float inv = LOG2E / (sqrtf(ss) + 1e-8f);
    uint2 pk;
    pk.x = f2bf(v.x*inv) | (f2bf(v.y*inv) << 16);
    pk.y = f2bf(v.z*inv) | (f2bf(v.w*inv) << 16);
    const int p = c >> 1, m = (c & 1) * 16 + r;
    const int i = sub >> 2;            // K 16-chunk
    const int h = (sub >> 1) & 1;      // wave-half's k range
    const int j4 = sub & 1;            // which uint2 inside the 16 B unit
    const size_t unit = ((size_t)(d * PAIRS + p) * 8 + i) * 64 + h * 32 + m;
    *(uint2*)(sws + unit * 8 + j4 * 4) = pk;
}

// ---------------- kernel 2: matching loss — class-split across 4 waves ------
__global__ __launch_bounds__(256, 4)
void matching_kernel(const float* __restrict__ emb,
                     const u16* __restrict__ sws,
                     float* __restrict__ slots,     // 32 floats, pre-zeroed
                     unsigned* __restrict__ counter, // pre-zeroed
                     float* __restrict__ out)
{
    // Query B-frags, XOR-swizzled: 16B unit phys(q,i,h) = q*16 + (i^(q&7))*2 + h
    // -> b128 frag reads land 8 words/bank (optimal).
    __shared__ __align__(16) unsigned char sB[64 * 256];  // 16 KB
    __shared__ float4 comb[64 * 4];                       // 4 KB: [query][wave]

    const int tid  = threadIdx.x;
    const int lane = tid & 63;
    const int w    = tid >> 6;
    const int bid  = blockIdx.x;
    const int d    = bid / BPD;
    const int j0   = (bid % BPD) * 64;
    const int n    = lane & 31;              // query column within set
    const int h    = lane >> 5;              // wave half = K-half

    // ---- stage 64 queries cooperatively: fp32 load, normalize, bf16 LDS ----
    {
        const float* ebase = emb + (size_t)d * (LNUM * SPC) * DIM;
        const int sub = lane & 31, hf = lane >> 5;
        for (int q = w * 2 + hf; q < 64; q += 8) {
            int qd  = j0 + q;
            int row = (qd / QNUM) * SPC + SNUM + (qd % QNUM);
            const float4 v = *(const float4*)(ebase + (size_t)row * DIM + sub * 4);
            float ss = v.x*v.x + v.y*v.y + v.z*v.z + v.w*v.w;
            #pragma unroll
            for (int off = 16; off >= 1; off >>= 1) ss += __shfl_xor(ss, off);
            float inv = 1.0f / (sqrtf(ss) + 1e-8f);
            uint2 pk;
            pk.x = f2bf(v.x*inv) | (f2bf(v.y*inv) << 16);
            pk.y = f2bf(v.z*inv) | (f2bf(v.w*inv) << 16);
            int i  = sub >> 2;               // k 16-chunk
            int hh = (sub >> 1) & 1;         // k half
            int j4 = sub & 1;
            int phys = q * 16 + ((i ^ (q & 7)) * 2) + hh;
            *(uint2*)(sB + phys * 16 + j4 * 8) = pk;
        }
    }
    __syncthreads();

    // ---- each wave reads all 64 queries' B-frags (16 x ds_read_b128) ----
    bf16x8 Bf[2][8];
    int ct[2];
    #pragma unroll
    for (int t = 0; t < 2; t++) {
        const int q = t * 32 + n;
        ct[t] = (j0 + q) / QNUM;             // true class (labels are identity)
        #pragma unroll
        for (int i = 0; i < 8; i++) {
            int phys = q * 16 + ((i ^ (n & 7)) * 2) + h;
            Bf[t][i] = *(const bf16x8*)(sB + phys * 16);
        }
    }

    // ---- support stream: wave w handles pair-tiles w, w+4, ..., w+28 ----
    const bool am = (lane & 15) < SNUM;      // pad rows: m%16 >= 10
    const u16* av = sws + ((size_t)(d * PAIRS) + w) * 4096 + lane * 8;

    bf16x8 Af[8] = {};                       // zeros persist in pad lanes
    float tot[2] = {0.f, 0.f}, tv[2] = {0.f, 0.f}, mx[2] = {-1e30f, -1e30f};
    int   mi[2] = {0, 0};

    #pragma unroll 1
    for (int it = 0; it < 8; it++) {
        if (am) {
            #pragma unroll
            for (int i = 0; i < 8; i++)
                Af[i] = *(const bf16x8*)(av + i * 512);  // frag i at +1024 B
        }
        av += 4 * 4096;

        f32x16 acc0 = {}, acc1 = {};
        #pragma unroll
        for (int i = 0; i < 8; i++) {
            acc0 = __builtin_amdgcn_mfma_f32_32x32x16_bf16(Af[i], Bf[0][i], acc0, 0, 0, 0);
            acc1 = __builtin_amdgcn_mfma_f32_32x32x16_bf16(Af[i], Bf[1][i], acc1, 0, 0, 0);
        }

        // C: col=lane&31 (query), row=(reg&3)+8*(reg>>2)+4h. class0 = regs
        // 0..7, class1 = regs 8..15; 6 pad rows/class give exp2(0)=1 ->
        // deferred -6 correction (shift-invariant for argmax).
        const int tile = it * 4 + w, c0 = 2 * tile, c1 = c0 + 1;
        #pragma unroll
        for (int t = 0; t < 2; t++) {
            const f32x16 a = t ? acc1 : acc0;
            float p0 = 0.f, p1 = 0.f;
            #pragma unroll
            for (int r = 0; r < 8; r++)  p0 += EXP2(a[r]);
            #pragma unroll
            for (int r = 8; r < 16; r++) p1 += EXP2(a[r]);
            float s0 = p0 + __shfl_xor(p0, 32);
            float s1 = p1 + __shfl_xor(p1, 32);
            tot[t] += s0 + s1;
            float sb = (s1 > s0) ? s1 : s0;  // strict > keeps lower class on tie
            int   cb = (s1 > s0) ? c1 : c0;
            bool better = sb > mx[t];
            mx[t] = better ? sb : mx[t];
            mi[t] = better ? cb : mi[t];
            tv[t] = (c0 == ct[t]) ? s0 : tv[t];
            tv[t] = (c1 == ct[t]) ? s1 : tv[t];
        }
    }

    // ---- combine the 4 waves' 16-class partials per query ----
    if (h == 0) {
        #pragma unroll
        for (int t = 0; t < 2; t++)
            comb[(t * 32 + n) * 4 + w] =
                make_float4(tot[t], tv[t], mx[t], __builtin_bit_cast(float, mi[t]));
    }
    __syncthreads();

    if (w == 0) {
        const int q = lane;                  // lane -> query 0..63
        float tt = 0.f, vv = 0.f, bmx = -1e30f; int bmi = 1 << 30;
        #pragma unroll
        for (int ww = 0; ww < 4; ww++) {
            float4 c = comb[q * 4 + ww];
            tt += c.x; vv += c.y;
            int ii = __builtin_bit_cast(int, c.w);
            bool better = (c.z > bmx) || (c.z == bmx && ii < bmi);
            bmx = better ? c.z : bmx;
            bmi = better ? ii  : bmi;
        }
        const int ctq = (j0 + q) / QNUM;
        float p = (vv - 6.0f) / (tt - 384.0f);
        p = fminf(fmaxf(p, 1e-8f), 1.0f);
        float nll = -__logf(p);
        float cor = (bmi == ctq) ? 1.0f : 0.0f;
        #pragma unroll
        for (int off = 1; off < 64; off <<= 1) {
            nll += __shfl_xor(nll, off);
            cor += __shfl_xor(cor, off);
        }
        if (lane == 0) {
            atomicAdd(&slots[bid & 15], nll);        // spread over 16 lines' worth
            atomicAdd(&slots[16 + (bid & 15)], cor);
        }
        __threadfence();
        unsigned last = 0;
        if (lane == 0) last = (atomicAdd(counter, 1u) == (unsigned)(NBLK - 1)) ? 1u : 0u;
        last = __shfl((int)last, 0);
        if (last) {
            float v2 = 0.f;
            if (lane < 32) v2 = atomicAdd(&slots[lane], 0.0f);  // coherent read
            #pragma unroll
            for (int off = 8; off >= 1; off >>= 1) v2 += __shfl_xor(v2, off);
            float lossS = __shfl(v2, 0);
            float corS  = __shfl(v2, 16);
            if (lane == 0) {
                const float sc = 1.0f / (float)(DNUM * QPD);
                out[0] = lossS * sc;
                out[1] = corS * sc;
            }
        }
    }
}

extern "C" void kernel_launch(void* const* d_in, const int* in_sizes, int n_in,
                              void* d_out, int out_size, void* d_ws, size_t ws_size,
                              hipStream_t stream) {
    (void)in_sizes; (void)n_in; (void)out_size; (void)ws_size;
    const float* emb = (const float*)d_in[0];
    // d_in[1] (labels) unused: identity class mapping by construction.
    float* out = (float*)d_out;

    float*    slots   = (float*)d_ws;                       // 32 floats
    unsigned* counter = (unsigned*)((char*)d_ws + 128);
    u16*      sws     = (u16*)((char*)d_ws + 256);          // 16.78 MB frag-ordered supports

    hipMemsetAsync(d_ws, 0, 132, stream);                   // zero slots + counter
    norm_sup<<<DNUM * SPD / 8, 256, 0, stream>>>(emb, sws);
    matching_kernel<<<NBLK, 256, 0, stream>>>(emb, sws, slots, counter, out);
}

// Round 9
// 235.145 us; speedup vs baseline: 1.5585x; 1.5585x over previous
//
#include <hip/hip_runtime.h>
#include <hip/hip_bf16.h>

#define DNUM 64
#define LNUM 64
#define SNUM 10
#define QNUM 30
#define SPC  40
#define DIM  128
#define QPD  (LNUM*QNUM)    // 1920 queries per domain
#define SPD  (LNUM*SNUM)    // 640 supports per domain
#define PAIRS 32            // 32 class-pair tiles (2 classes x 16 rows each)
#define BPD  (QPD/64)       // 30 blocks per domain (64 queries/block)
#define NBLK (DNUM*BPD)     // 1920 blocks x 4 waves = 7680 waves
#define LOG2E 1.44269504088896340736f

typedef __bf16 bf16x8 __attribute__((ext_vector_type(8)));
typedef float  f32x16 __attribute__((ext_vector_type(16)));
typedef unsigned int u32;
typedef unsigned short u16;

#if __has_builtin(__builtin_amdgcn_exp2f)
#define EXP2(x) __builtin_amdgcn_exp2f(x)
#else
#define EXP2(x) exp2f(x)
#endif

static __device__ __forceinline__ u32 f2bf(float x) {
    __bf16 h = (__bf16)x;
    return (u32)__builtin_bit_cast(u16, h);
}

// ---------------- kernel 1: normalize supports (x log2e) -> 32x32 A-frag order
// Tile p of domain d holds classes 2p (rows 0..9) and 2p+1 (rows 16..25);
// rows 10..15/26..31 are pad (never stored, never read). 16 B units:
// unit ((d*32+p)*8 + i)*64 + h*32 + m holds A[m][k=i*16+h*8 .. +7], so the
// main kernel's lane l (m=l&31, h=l>>5) reads frag i as one dwordx4 at
// tile_base + i*1024 + l*16 — consecutive lanes, consecutive 16 B. Supports
// carry the log2e factor so the main kernel uses native exp2. (verified R7)
__global__ __launch_bounds__(256)
void norm_sup(const float* __restrict__ emb, u16* __restrict__ sws)
{
    const int hw  = (blockIdx.x * 256 + threadIdx.x) >> 5;  // support row id
    const int sub = threadIdx.x & 31;                       // k = sub*4 .. +3
    const int d = hw / SPD, s = hw % SPD;
    const int c = s / SNUM, r = s % SNUM;
    const float4 v = *(const float4*)(emb + ((size_t)d * (LNUM * SPC) + c * SPC + r) * DIM + sub * 4);
    float ss = v.x*v.x + v.y*v.y + v.z*v.z + v.w*v.w;
    #pragma unroll
    for (int off = 16; off >= 1; off >>= 1) ss += __shfl_xor(ss, off);
    const float inv = LOG2E / (sqrtf(ss) + 1e-8f);
    uint2 pk;
    pk.x = f2bf(v.x*inv) | (f2bf(v.y*inv) << 16);
    pk.y = f2bf(v.z*inv) | (f2bf(v.w*inv) << 16);
    const int p = c >> 1, m = (c & 1) * 16 + r;
    const int i = sub >> 2;            // K 16-chunk
    const int h = (sub >> 1) & 1;      // wave-half's k range
    const int j4 = sub & 1;            // which uint2 inside the 16 B unit
    const size_t unit = ((size_t)(d * PAIRS + p) * 8 + i) * 64 + h * 32 + m;
    *(uint2*)(sws + unit * 8 + j4 * 4) = pk;
}

// ---------------- kernel 2: matching loss — class-split across 4 waves ------
// NOTE (R8 post-mortem): no device-scope fences/atomic counters here — a
// __threadfence per block invalidated per-XCD L2 and tripled HBM traffic.
__global__ __launch_bounds__(256, 4)
void matching_kernel(const float* __restrict__ emb,
                     const u16* __restrict__ sws,
                     float2* __restrict__ partials)   // one per block
{
    // Query B-frags, XOR-swizzled: 16B unit phys(q,i,h) = q*16 + (i^(q&7))*2 + h
    __shared__ __align__(16) unsigned char sB[64 * 256];  // 16 KB
    __shared__ float4 comb[64 * 5];                       // 5120 B: [query][wave], stride 5

    const int tid  = threadIdx.x;
    const int lane = tid & 63;
    const int w    = tid >> 6;
    const int bid  = blockIdx.x;
    const int d    = bid / BPD;
    const int j0   = (bid % BPD) * 64;
    const int n    = lane & 31;              // query column within set
    const int h    = lane >> 5;              // wave half = K-half

    // ---- stage 64 queries cooperatively: fp32 load, normalize, bf16 LDS ----
    {
        const float* ebase = emb + (size_t)d * (LNUM * SPC) * DIM;
        const int sub = lane & 31, hf = lane >> 5;
        for (int q = w * 2 + hf; q < 64; q += 8) {
            int qd  = j0 + q;
            int row = (qd / QNUM) * SPC + SNUM + (qd % QNUM);
            const float4 v = *(const float4*)(ebase + (size_t)row * DIM + sub * 4);
            float ss = v.x*v.x + v.y*v.y + v.z*v.z + v.w*v.w;
            #pragma unroll
            for (int off = 16; off >= 1; off >>= 1) ss += __shfl_xor(ss, off);
            float inv = 1.0f / (sqrtf(ss) + 1e-8f);
            uint2 pk;
            pk.x = f2bf(v.x*inv) | (f2bf(v.y*inv) << 16);
            pk.y = f2bf(v.z*inv) | (f2bf(v.w*inv) << 16);
            int i  = sub >> 2;               // k 16-chunk
            int hh = (sub >> 1) & 1;         // k half
            int j4 = sub & 1;
            int phys = q * 16 + ((i ^ (q & 7)) * 2) + hh;
            *(uint2*)(sB + phys * 16 + j4 * 8) = pk;
        }
    }
    __syncthreads();

    // ---- each wave reads all 64 queries' B-frags (16 x ds_read_b128) ----
    bf16x8 Bf[2][8];
    int ct[2];
    #pragma unroll
    for (int t = 0; t < 2; t++) {
        const int q = t * 32 + n;
        ct[t] = (j0 + q) / QNUM;             // true class (labels are identity)
        #pragma unroll
        for (int i = 0; i < 8; i++) {
            int phys = q * 16 + ((i ^ (n & 7)) * 2) + h;
            Bf[t][i] = *(const bf16x8*)(sB + phys * 16);
        }
    }

    // ---- support stream: wave w handles pair-tiles w, w+4, ..., w+28 ----
    const bool am = (lane & 15) < SNUM;      // pad rows: m%16 >= 10
    const u16* av = sws + ((size_t)(d * PAIRS) + w) * 4096 + lane * 8;

    bf16x8 Af[8] = {};                       // zeros persist in pad lanes
    float tot[2] = {0.f, 0.f}, tv[2] = {0.f, 0.f}, mx[2] = {-1e30f, -1e30f};
    int   mi[2] = {0, 0};

    #pragma unroll 1
    for (int it = 0; it < 8; it++) {
        if (am) {
            #pragma unroll
            for (int i = 0; i < 8; i++)
                Af[i] = *(const bf16x8*)(av + i * 512);  // frag i at +1024 B
        }
        av += 4 * 4096;

        f32x16 acc0 = {}, acc1 = {};
        #pragma unroll
        for (int i = 0; i < 8; i++) {
            acc0 = __builtin_amdgcn_mfma_f32_32x32x16_bf16(Af[i], Bf[0][i], acc0, 0, 0, 0);
            acc1 = __builtin_amdgcn_mfma_f32_32x32x16_bf16(Af[i], Bf[1][i], acc1, 0, 0, 0);
        }

        // C: col=lane&31 (query), row=(reg&3)+8*(reg>>2)+4h. class0 = regs
        // 0..7, class1 = regs 8..15; 6 pad rows/class give exp2(0)=1 ->
        // deferred -6 correction (shift-invariant for argmax).
        const int tile = it * 4 + w, c0 = 2 * tile, c1 = c0 + 1;
        #pragma unroll
        for (int t = 0; t < 2; t++) {
            const f32x16 a = t ? acc1 : acc0;
            float p0 = 0.f, p1 = 0.f;
            #pragma unroll
            for (int r = 0; r < 8; r++)  p0 += EXP2(a[r]);
            #pragma unroll
            for (int r = 8; r < 16; r++) p1 += EXP2(a[r]);
            float s0 = p0 + __shfl_xor(p0, 32);
            float s1 = p1 + __shfl_xor(p1, 32);
            tot[t] += s0 + s1;
            float sb = (s1 > s0) ? s1 : s0;  // strict > keeps lower class on tie
            int   cb = (s1 > s0) ? c1 : c0;
            bool better = sb > mx[t];
            mx[t] = better ? sb : mx[t];
            mi[t] = better ? cb : mi[t];
            tv[t] = (c0 == ct[t]) ? s0 : tv[t];
            tv[t] = (c1 == ct[t]) ? s1 : tv[t];
        }
    }

    // ---- combine the 4 waves' 16-class partials per query ----
    if (h == 0) {
        #pragma unroll
        for (int t = 0; t < 2; t++)
            comb[(t * 32 + n) * 5 + w] =
                make_float4(tot[t], tv[t], mx[t], __builtin_bit_cast(float, mi[t]));
    }
    __syncthreads();

    if (w == 0) {
        const int q = lane;                  // lane -> query 0..63
        float tt = 0.f, vv = 0.f, bmx = -1e30f; int bmi = 1 << 30;
        #pragma unroll
        for (int ww = 0; ww < 4; ww++) {
            float4 c = comb[q * 5 + ww];
            tt += c.x; vv += c.y;
            int ii = __builtin_bit_cast(int, c.w);
            bool better = (c.z > bmx) || (c.z == bmx && ii < bmi);
            bmx = better ? c.z : bmx;
            bmi = better ? ii  : bmi;
        }
        const int ctq = (j0 + q) / QNUM;
        float p = (vv - 6.0f) / (tt - 384.0f);
        p = fminf(fmaxf(p, 1e-8f), 1.0f);
        float nll = -__logf(p);
        float cor = (bmi == ctq) ? 1.0f : 0.0f;
        #pragma unroll
        for (int off = 1; off < 64; off <<= 1) {
            nll += __shfl_xor(nll, off);
            cor += __shfl_xor(cor, off);
        }
        if (lane == 0) partials[bid] = make_float2(nll, cor);
    }
}

// ---------------- kernel 3: reduce per-block partials -> 2 outputs ----------
__global__ __launch_bounds__(256)
void reduce_partials(const float2* __restrict__ p, float* __restrict__ out)
{
    __shared__ float2 sm[4];
    float a = 0.f, b = 0.f;
    for (int i = threadIdx.x; i < NBLK; i += 256) {
        float2 v = p[i];
        a += v.x; b += v.y;
    }
    #pragma unroll
    for (int off = 1; off < 64; off <<= 1) {
        a += __shfl_xor(a, off);
        b += __shfl_xor(b, off);
    }
    const int w = threadIdx.x >> 6;
    if ((threadIdx.x & 63) == 0) sm[w] = make_float2(a, b);
    __syncthreads();
    if (threadIdx.x == 0) {
        float A = 0.f, B = 0.f;
        #pragma unroll
        for (int i = 0; i < 4; i++) { A += sm[i].x; B += sm[i].y; }
        const float sc = 1.0f / (float)(DNUM * QPD);
        out[0] = A * sc;
        out[1] = B * sc;
    }
}

extern "C" void kernel_launch(void* const* d_in, const int* in_sizes, int n_in,
                              void* d_out, int out_size, void* d_ws, size_t ws_size,
                              hipStream_t stream) {
    (void)in_sizes; (void)n_in; (void)out_size; (void)ws_size;
    const float* emb = (const float*)d_in[0];
    // d_in[1] (labels) unused: identity class mapping by construction.
    float* out = (float*)d_out;

    float2* parts = (float2*)d_ws;                          // 1920 float2 = 15360 B
    u16*    sws   = (u16*)((char*)d_ws + 16384);            // 16.78 MB frag-ordered supports

    norm_sup<<<DNUM * SPD / 8, 256, 0, stream>>>(emb, sws);
    matching_kernel<<<NBLK, 256, 0, stream>>>(emb, sws, parts);
    reduce_partials<<<1, 256, 0, stream>>>(parts, out);
}